// Round 1
// baseline (320.861 us; speedup 1.0000x reference)
//
#include <hip/hip_runtime.h>

typedef __attribute__((ext_vector_type(8))) short short8;
typedef __attribute__((ext_vector_type(4))) short short4v;
typedef __attribute__((ext_vector_type(4))) float f32x4;

#define MFMA16 __builtin_amdgcn_mfma_f32_16x16x32_bf16

// bf16 split by truncation: x = hi + lo (lo captures next 8 mantissa bits).
__device__ __forceinline__ short bf16t(float f) {
  return (short)(__float_as_uint(f) >> 16);
}
__device__ __forceinline__ float bf16f(short h) {
  return __uint_as_float(((unsigned)(unsigned short)h) << 16);
}

// ---------------------------------------------------------------------------
// Symmetric-X 64x64 fp32 matmul in LDS: D = X^T * Y (== X*Y, X symmetric).
// ---------------------------------------------------------------------------
__device__ __forceinline__ void mm64(const float* X, const float* Y, float* D,
                                     int tid) {
  const int R = (tid >> 4) << 2;
  const int Cc = (tid & 15) << 2;
  float acc[4][4];
#pragma unroll
  for (int i = 0; i < 4; i++)
#pragma unroll
    for (int j = 0; j < 4; j++) acc[i][j] = 0.f;
#pragma unroll 4
  for (int kk = 0; kk < 64; kk++) {
    f32x4 a = *(const f32x4*)&X[(kk << 6) + R];
    f32x4 bb = *(const f32x4*)&Y[(kk << 6) + Cc];
#pragma unroll
    for (int i = 0; i < 4; i++)
#pragma unroll
      for (int j = 0; j < 4; j++) acc[i][j] = fmaf(a[i], bb[j], acc[i][j]);
  }
#pragma unroll
  for (int i = 0; i < 4; i++) {
    f32x4 r = {acc[i][0], acc[i][1], acc[i][2], acc[i][3]};
    *(f32x4*)&D[((R + i) << 6) + Cc] = r;
  }
  __syncthreads();
}

// ---------------------------------------------------------------------------
// Stage 1 (MFMA): sigma second moments + rowsums, atomically accumulated.
// grid 1024 = b(32) x k(4) x pc(8); block 256 = 4 waves; wave w owns g-rows
// 16w..16w+15. Shared double-buffered bf16 hi/lo tile [ch64][px64] stride 72.
// 1 barrier per 64-px chunk; register prefetch of next chunk.
// ---------------------------------------------------------------------------
__global__ __launch_bounds__(256, 4) void k_stats(const float* __restrict__ x,
                                                  const int* __restrict__ idx,
                                                  float* __restrict__ sigw,
                                                  float* __restrict__ rsum) {
  __shared__ __align__(16) short XT[2][2 * 64 * 72];  // per buf: hi | lo
  __shared__ int chan[64];
  const int tid = threadIdx.x;
  const int w = tid >> 6, lane = tid & 63;
  const int q = lane >> 4, n15 = lane & 15;
  const int u = tid >> 4;     // 0..15 (channel sub-row)
  const int quad = tid & 15;  // px quad
  const int blk = blockIdx.x;
  const int b = blk >> 5, k = (blk >> 3) & 3, pc = blk & 7;

  if (tid < 64) chan[tid] = idx[(tid << 2) + k];
  __syncthreads();

  const float* xb = x + ((size_t)b << 20);
  const int pcbase = pc << 9;

  f32x4 acc[4];
#pragma unroll
  for (int t = 0; t < 4; t++) acc[t] = (f32x4){0.f, 0.f, 0.f, 0.f};
  float rsp[4] = {0.f, 0.f, 0.f, 0.f};

  f32x4 vv[4];
#pragma unroll
  for (int i = 0; i < 4; i++)  // prolog: chunk 0
    vv[i] = *(const f32x4*)&xb[((size_t)chan[(i << 4) + u] << 12) + pcbase +
                               (quad << 2)];

  for (int c = 0; c < 8; c++) {
    short* XH = &XT[c & 1][0];
    short* XL = XH + 64 * 72;
    // convert + stage into LDS; accumulate rowsums
#pragma unroll
    for (int i = 0; i < 4; i++) {
      const int ch = (i << 4) + u;
      rsp[i] += vv[i][0] + vv[i][1] + vv[i][2] + vv[i][3];
      short4v hv, lv;
#pragma unroll
      for (int j = 0; j < 4; j++) {
        hv[j] = bf16t(vv[i][j]);
        lv[j] = bf16t(vv[i][j] - bf16f(hv[j]));
      }
      *(short4v*)&XH[ch * 72 + (quad << 2)] = hv;
      *(short4v*)&XL[ch * 72 + (quad << 2)] = lv;
    }
    // prefetch next chunk
    if (c < 7) {
      const int p0 = pcbase + ((c + 1) << 6);
#pragma unroll
      for (int i = 0; i < 4; i++)
        vv[i] = *(const f32x4*)&xb[((size_t)chan[(i << 4) + u] << 12) + p0 +
                                   (quad << 2)];
    }
    __syncthreads();
    // compute: wave w rows (A) x all hb rows (B)
#pragma unroll
    for (int s = 0; s < 2; s++) {
      const int ko = (s << 5) + (q << 3);
      const short8 ah = *(const short8*)&XH[((w << 4) + n15) * 72 + ko];
      const short8 al = *(const short8*)&XL[((w << 4) + n15) * 72 + ko];
#pragma unroll
      for (int hb = 0; hb < 4; hb++) {
        const short8 bh = *(const short8*)&XH[((hb << 4) + n15) * 72 + ko];
        const short8 bl = *(const short8*)&XL[((hb << 4) + n15) * 72 + ko];
        acc[hb] = MFMA16(ah, bh, acc[hb], 0, 0, 0);
        acc[hb] = MFMA16(ah, bl, acc[hb], 0, 0, 0);
        acc[hb] = MFMA16(al, bh, acc[hb], 0, 0, 0);
      }
    }
  }
  // rowsums: reduce across the 16 quad-lanes (same u), one atomic per channel
#pragma unroll
  for (int i = 0; i < 4; i++) {
    float r = rsp[i];
    r += __shfl_xor(r, 1);
    r += __shfl_xor(r, 2);
    r += __shfl_xor(r, 4);
    r += __shfl_xor(r, 8);
    if (quad == 0) atomicAdd(&rsum[(b << 6) + (i << 4) + u], r);
  }
  // sigma: C-layout row m=4q+r -> g = 16w+4q+r; col n15 -> h = 16hb+n15
  float* sb = sigw + ((size_t)b << 12);
#pragma unroll
  for (int hb = 0; hb < 4; hb++)
#pragma unroll
    for (int r = 0; r < 4; r++)
      atomicAdd(&sb[(((w << 4) + (q << 2) + r) << 6) + (hb << 4) + n15],
                acc[hb][r]);
}

// ---------------------------------------------------------------------------
// Stage 2: mean + sigma_N build + Newton-Schulz (T=5), fp32 LDS. 1 block/batch.
// ---------------------------------------------------------------------------
__global__ __launch_bounds__(256) void k_ns(const float* __restrict__ sigw,
                                            const float* __restrict__ rsum,
                                            float* __restrict__ meanw,
                                            float* __restrict__ wmw) {
  __shared__ __align__(16) float SN[4096];
  __shared__ __align__(16) float Pm[4096];
  __shared__ __align__(16) float Ta[4096];
  __shared__ __align__(16) float Tb[4096];
  __shared__ float ml[64];
  __shared__ float tr_s;
  const int tid = threadIdx.x;
  const int b = blockIdx.x;

  if (tid < 64) {
    const float mu = rsum[(b << 6) + tid] * (1.f / 16384.f);
    ml[tid] = mu;
    meanw[(b << 6) + tid] = mu;
  }
  __syncthreads();
#pragma unroll
  for (int i = 0; i < 16; i++) {
    const int e = (i << 8) + tid;
    const int g = e >> 6, h = e & 63;
    SN[e] = sigw[(b << 12) + e] * (1.f / 16384.f) - ml[g] * ml[h];
  }
  __syncthreads();
  if (tid < 64) {
    float d = SN[tid * 65];
#pragma unroll
    for (int off = 32; off; off >>= 1) d += __shfl_down(d, off);
    if (tid == 0) tr_s = 1.f / d;
  }
  __syncthreads();
  const float trinv = tr_s;
#pragma unroll
  for (int i = 0; i < 16; i++) {
    const int e = (i << 8) + tid;
    SN[e] *= trinv;
    Pm[e] = ((e >> 6) == (e & 63)) ? 1.f : 0.f;
  }
  __syncthreads();

  const int R4 = (tid >> 4) << 2, C4 = (tid & 15) << 2;
  for (int it = 0; it < 5; it++) {
    float p2[4][4], ps[4][4];
#pragma unroll
    for (int i = 0; i < 4; i++)
#pragma unroll
      for (int j = 0; j < 4; j++) {
        p2[i][j] = 0.f;
        ps[i][j] = 0.f;
      }
#pragma unroll 4
    for (int kk = 0; kk < 64; kk++) {
      f32x4 a = *(const f32x4*)&Pm[(kk << 6) + R4];
      f32x4 bp = *(const f32x4*)&Pm[(kk << 6) + C4];
      f32x4 bs = *(const f32x4*)&SN[(kk << 6) + C4];
#pragma unroll
      for (int i = 0; i < 4; i++)
#pragma unroll
        for (int j = 0; j < 4; j++) {
          p2[i][j] = fmaf(a[i], bp[j], p2[i][j]);
          ps[i][j] = fmaf(a[i], bs[j], ps[i][j]);
        }
    }
#pragma unroll
    for (int i = 0; i < 4; i++) {
      f32x4 r1 = {p2[i][0], p2[i][1], p2[i][2], p2[i][3]};
      f32x4 r2 = {ps[i][0], ps[i][1], ps[i][2], ps[i][3]};
      *(f32x4*)&Ta[((R4 + i) << 6) + C4] = r1;
      *(f32x4*)&Tb[((R4 + i) << 6) + C4] = r2;
    }
    __syncthreads();
    float t3[4][4];
#pragma unroll
    for (int i = 0; i < 4; i++)
#pragma unroll
      for (int j = 0; j < 4; j++) t3[i][j] = 0.f;
#pragma unroll 4
    for (int kk = 0; kk < 64; kk++) {
      f32x4 a = *(const f32x4*)&Ta[(kk << 6) + R4];
      f32x4 bb = *(const f32x4*)&Tb[(kk << 6) + C4];
#pragma unroll
      for (int i = 0; i < 4; i++)
#pragma unroll
        for (int j = 0; j < 4; j++) t3[i][j] = fmaf(a[i], bb[j], t3[i][j]);
    }
#pragma unroll
    for (int i = 0; i < 4; i++) {
      f32x4 p = *(const f32x4*)&Pm[((R4 + i) << 6) + C4];
#pragma unroll
      for (int j = 0; j < 4; j++) p[j] = 1.5f * p[j] - 0.5f * t3[i][j];
      *(f32x4*)&Pm[((R4 + i) << 6) + C4] = p;
    }
    __syncthreads();
  }
  const float s = sqrtf(trinv);
#pragma unroll
  for (int i = 0; i < 16; i++) {
    const int e = (i << 8) + tid;
    wmw[(b << 12) + e] = Pm[e] * s;
  }
}

// ---------------------------------------------------------------------------
// Stage 3+4 fused: per-block redundant batch sqrtvar (ddof=1, two-pass, reads
// are L2-resident) computed into Sv (aliased onto Al's LDS, dead until mm64);
// then gamma = triu(wir)+triu(wir,1)^T; A = gamma@wm (fp32);
// ofs = mean + eps2*svm - A@mean; A exported as bf16 hi/lo pair.
// ---------------------------------------------------------------------------
__global__ __launch_bounds__(256) void k_gA(
    const float* __restrict__ wmw, const float* __restrict__ meanw,
    const float* __restrict__ eps1, const float* __restrict__ eps2,
    short* __restrict__ Ahl, float* __restrict__ ofsw) {
  __shared__ __align__(16) float Wl[4096];
  __shared__ __align__(16) float Gm[4096];
  __shared__ __align__(16) float Al[4096];  // doubles as Sv before mm64
  __shared__ float ml[64];
  __shared__ float svml[64];
  const int tid = threadIdx.x;
  const int b = blockIdx.x;
  float* Sv = Al;

  // sqrtvar(wm) across batch: thread owns 16 elements, two-pass for precision
#pragma unroll
  for (int i = 0; i < 16; i++) {
    const int e = (i << 8) + tid;
    float vv[32];
    float s = 0.f;
#pragma unroll
    for (int p = 0; p < 32; p++) {
      vv[p] = wmw[(p << 12) + e];
      s += vv[p];
    }
    const float mu = s * (1.f / 32.f);
    float s2 = 0.f;
#pragma unroll
    for (int p = 0; p < 32; p++) {
      const float d = vv[p] - mu;
      s2 = fmaf(d, d, s2);
    }
    Sv[e] = sqrtf(s2 * (1.f / 31.f) + 1e-5f);
  }
  // sqrtvar(mean) across batch + own-batch mean row
  if (tid < 64) {
    ml[tid] = meanw[(b << 6) + tid];
    float vv[32];
    float s = 0.f;
#pragma unroll
    for (int p = 0; p < 32; p++) {
      vv[p] = meanw[(p << 6) + tid];
      s += vv[p];
    }
    const float mu = s * (1.f / 32.f);
    float s2 = 0.f;
#pragma unroll
    for (int p = 0; p < 32; p++) {
      const float d = vv[p] - mu;
      s2 = fmaf(d, d, s2);
    }
    svml[tid] = sqrtf(s2 * (1.f / 31.f) + 1e-5f);
  }
#pragma unroll
  for (int i = 0; i < 16; i++) {
    const int e = (i << 8) + tid;
    Wl[e] = wmw[(b << 12) + e];
  }
  __syncthreads();
#pragma unroll
  for (int i = 0; i < 16; i++) {
    const int e = (i << 8) + tid;
    const int g = e >> 6, h = e & 63;
    const int eu = (h >= g) ? e : ((h << 6) + g);  // mirror lower from upper
    Gm[e] = Wl[eu] + eps1[(b << 12) + eu] * Sv[eu];
  }
  __syncthreads();
  mm64(Gm, Wl, Al, tid);  // Al = gamma @ wm (Gm bitwise symmetric); kills Sv
  short* Ab = Ahl + ((size_t)b << 13);
#pragma unroll
  for (int i = 0; i < 16; i++) {
    const int e = (i << 8) + tid;
    const float a = Al[e];
    const short h2 = bf16t(a);
    Ab[e] = h2;
    Ab[4096 + e] = bf16t(a - bf16f(h2));
  }
  if (tid < 64) {
    float dot = 0.f;
    for (int h = 0; h < 64; h++) dot = fmaf(Al[(tid << 6) + h], ml[h], dot);
    ofsw[(b << 6) + tid] = ml[tid] + eps2[(b << 6) + tid] * svml[tid] - dot;
  }
}

// ---------------------------------------------------------------------------
// Stage 5 (MFMA): out[b, idx[4g+k], p] = sum_h A[g,h] x[b, idx[4h+k], p] + ofs.
// block 256 = 4 waves; wave w owns g-rows 16w..16w+15; A-frags loaded ONCE
// from global into registers (as the MFMA *B*-operand). X staged transposed
// as bf16 hi/lo [px64][h64] stride 72, converted ONCE at staging time,
// double-buffered. Operand order D = X^T(A-op) x A(B-op) puts px in the acc
// register index -> f32x4 stores (4/chunk instead of 16 scalar).
// grid 1024 = b(32) x k(4) x pc(8); 1 barrier per 64-px chunk.
// ---------------------------------------------------------------------------
__global__ __launch_bounds__(256, 4) void k_apply(const float* __restrict__ x,
                                                  const int* __restrict__ idx,
                                                  const short* __restrict__ Ahl,
                                                  const float* __restrict__ ofsw,
                                                  float* __restrict__ out) {
  __shared__ __align__(16) short XT[2][2 * 64 * 72];  // per buf: hi | lo
  __shared__ int chan[64];
  const int tid = threadIdx.x;
  const int w = tid >> 6, lane = tid & 63;
  const int q = lane >> 4, n15 = lane & 15;
  const int blk = blockIdx.x;
  const int b = blk >> 5, k = (blk >> 3) & 3, pc = blk & 7;

  if (tid < 64) chan[tid] = idx[(tid << 2) + k];

  // A-matrix fragments direct from global (lane n15 = A-row g within gb=w)
  const short* Ab = Ahl + ((size_t)b << 13);
  short8 ah[2], al[2];
#pragma unroll
  for (int s = 0; s < 2; s++) {
    const int o = (((w << 4) + n15) << 6) + (s << 5) + (q << 3);
    ah[s] = *(const short8*)&Ab[o];
    al[s] = *(const short8*)&Ab[4096 + o];
  }
  const float of = ofsw[(b << 6) + (w << 4) + n15];
  __syncthreads();

  const float* xb = x + ((size_t)b << 20);
  float* outb = out + ((size_t)b << 20);
  const int pcbase = pc << 9;

  float v[16];
#pragma unroll
  for (int j = 0; j < 16; j++)  // prolog: chunk 0 (row chan[16w+j], px=lane)
    v[j] = xb[((size_t)chan[(w << 4) + j] << 12) + pcbase + lane];

  for (int c = 0; c < 8; c++) {
    short* XH = &XT[c & 1][0];
    short* XL = XH + 64 * 72;
    // stage transposed bf16 hi/lo: row px=lane, cols h = 16w..16w+15
#pragma unroll
    for (int jj = 0; jj < 4; jj++) {
      short4v hv, lv;
#pragma unroll
      for (int j = 0; j < 4; j++) {
        const float f = v[(jj << 2) + j];
        hv[j] = bf16t(f);
        lv[j] = bf16t(f - bf16f(hv[j]));
      }
      *(short4v*)&XH[lane * 72 + (w << 4) + (jj << 2)] = hv;
      *(short4v*)&XL[lane * 72 + (w << 4) + (jj << 2)] = lv;
    }
    if (c < 7) {
      const int p0n = pcbase + ((c + 1) << 6);
#pragma unroll
      for (int j = 0; j < 16; j++)
        v[j] = xb[((size_t)chan[(w << 4) + j] << 12) + p0n + lane];
    }
    __syncthreads();

    const int p0 = pcbase + (c << 6);
    f32x4 acc[4];
#pragma unroll
    for (int nb = 0; nb < 4; nb++) acc[nb] = (f32x4){of, of, of, of};
#pragma unroll
    for (int s = 0; s < 2; s++) {
#pragma unroll
      for (int nb = 0; nb < 4; nb++) {
        const int ro = ((nb << 4) + n15) * 72 + (s << 5) + (q << 3);
        const short8 xh = *(const short8*)&XH[ro];
        const short8 xl = *(const short8*)&XL[ro];
        acc[nb] = MFMA16(xh, ah[s], acc[nb], 0, 0, 0);
        acc[nb] = MFMA16(xl, ah[s], acc[nb], 0, 0, 0);
        acc[nb] = MFMA16(xh, al[s], acc[nb], 0, 0, 0);
      }
    }
    // stores: C-layout row = q*4+reg = px within tile nb, col = n15 = g.
    // Each lane: 4 consecutive px of one channel -> one f32x4 per nb.
#pragma unroll
    for (int nb = 0; nb < 4; nb++) {
      *(f32x4*)&outb[((size_t)chan[(w << 4) + n15] << 12) + p0 + (nb << 4) +
                     (q << 2)] = acc[nb];
    }
  }
}

// ---------------------------------------------------------------------------
// ws layout (floats): sigw@0 (131072, zeroed) | rsum@131072 (2048, zeroed)
//  | meanw@133120 (2048) | wmw@135168 (131072) | (gap: former svw/svm)
//  | ofsw@270400 (2048) | Ahl@272448 (short[262144]).
// ---------------------------------------------------------------------------
extern "C" void kernel_launch(void* const* d_in, const int* in_sizes, int n_in,
                              void* d_out, int out_size, void* d_ws,
                              size_t ws_size, hipStream_t stream) {
  const float* x = (const float*)d_in[0];
  const int* idx = (const int*)d_in[1];
  const float* eps1 = (const float*)d_in[2];
  const float* eps2 = (const float*)d_in[3];
  float* out = (float*)d_out;
  float* ws = (float*)d_ws;

  float* sigw = ws;
  float* rsum = ws + 131072;
  float* meanw = ws + 133120;
  float* wmw = ws + 135168;
  float* ofsw = ws + 270400;
  short* Ahl = (short*)(ws + 272448);

  hipMemsetAsync(ws, 0, (131072 + 2048) * sizeof(float), stream);
  k_stats<<<1024, 256, 0, stream>>>(x, idx, sigw, rsum);
  k_ns<<<32, 256, 0, stream>>>(sigw, rsum, meanw, wmw);
  k_gA<<<32, 256, 0, stream>>>(wmw, meanw, eps1, eps2, Ahl, ofsw);
  k_apply<<<1024, 256, 0, stream>>>(x, idx, Ahl, ofsw, out);
}

// Round 3
// 299.538 us; speedup vs baseline: 1.0712x; 1.0712x over previous
//
#include <hip/hip_runtime.h>

typedef __attribute__((ext_vector_type(8))) short short8;
typedef __attribute__((ext_vector_type(4))) short short4v;
typedef __attribute__((ext_vector_type(4))) float f32x4;

#define MFMA16 __builtin_amdgcn_mfma_f32_16x16x32_bf16

// bf16 split by truncation: x = hi + lo (lo captures next 8 mantissa bits).
__device__ __forceinline__ short bf16t(float f) {
  return (short)(__float_as_uint(f) >> 16);
}
__device__ __forceinline__ float bf16f(short h) {
  return __uint_as_float(((unsigned)(unsigned short)h) << 16);
}

// Workgroup barrier WITHOUT the full __syncthreads memory drain: only LDS
// writes must be visible (lgkmcnt(0)); outstanding global prefetch loads /
// stores stay in flight across the barrier (avoids the vmcnt(0) drain the
// compiler emits for __syncthreads).
__device__ __forceinline__ void lds_barrier() {
  asm volatile("s_waitcnt lgkmcnt(0)" ::: "memory");
  __builtin_amdgcn_s_barrier();
  asm volatile("" ::: "memory");
}

// ---------------------------------------------------------------------------
// Symmetric-X 64x64 fp32 matmul in LDS: D = X^T * Y (== X*Y, X symmetric).
// ---------------------------------------------------------------------------
__device__ __forceinline__ void mm64(const float* X, const float* Y, float* D,
                                     int tid) {
  const int R = (tid >> 4) << 2;
  const int Cc = (tid & 15) << 2;
  float acc[4][4];
#pragma unroll
  for (int i = 0; i < 4; i++)
#pragma unroll
    for (int j = 0; j < 4; j++) acc[i][j] = 0.f;
#pragma unroll 4
  for (int kk = 0; kk < 64; kk++) {
    f32x4 a = *(const f32x4*)&X[(kk << 6) + R];
    f32x4 bb = *(const f32x4*)&Y[(kk << 6) + Cc];
#pragma unroll
    for (int i = 0; i < 4; i++)
#pragma unroll
      for (int j = 0; j < 4; j++) acc[i][j] = fmaf(a[i], bb[j], acc[i][j]);
  }
#pragma unroll
  for (int i = 0; i < 4; i++) {
    f32x4 r = {acc[i][0], acc[i][1], acc[i][2], acc[i][3]};
    *(f32x4*)&D[((R + i) << 6) + Cc] = r;
  }
  __syncthreads();
}

// ---------------------------------------------------------------------------
// Stage 1 (MFMA): sigma second moments + rowsums, atomically accumulated.
// grid 1024 = b(32) x k(4) x pc(8); block 256 = 4 waves; wave w owns g-rows
// 16w..16w+15. Shared double-buffered bf16 hi/lo tile [ch64][px64] stride 72.
// 1 raw barrier per 64-px chunk; register prefetch of next chunk stays in
// flight across the barrier (no vmcnt drain).
// ---------------------------------------------------------------------------
__global__ __launch_bounds__(256, 4) void k_stats(const float* __restrict__ x,
                                                  const int* __restrict__ idx,
                                                  float* __restrict__ sigw,
                                                  float* __restrict__ rsum) {
  __shared__ __align__(16) short XT[2][2 * 64 * 72];  // per buf: hi | lo
  __shared__ int chan[64];
  const int tid = threadIdx.x;
  const int w = tid >> 6, lane = tid & 63;
  const int q = lane >> 4, n15 = lane & 15;
  const int u = tid >> 4;     // 0..15 (channel sub-row)
  const int quad = tid & 15;  // px quad
  const int blk = blockIdx.x;
  const int b = blk >> 5, k = (blk >> 3) & 3, pc = blk & 7;

  if (tid < 64) chan[tid] = idx[(tid << 2) + k];
  __syncthreads();

  const float* xb = x + ((size_t)b << 20);
  const int pcbase = pc << 9;

  f32x4 acc[4];
#pragma unroll
  for (int t = 0; t < 4; t++) acc[t] = (f32x4){0.f, 0.f, 0.f, 0.f};
  float rsp[4] = {0.f, 0.f, 0.f, 0.f};

  f32x4 vv[4];
#pragma unroll
  for (int i = 0; i < 4; i++)  // prolog: chunk 0
    vv[i] = *(const f32x4*)&xb[((size_t)chan[(i << 4) + u] << 12) + pcbase +
                               (quad << 2)];

  for (int c = 0; c < 8; c++) {
    short* XH = &XT[c & 1][0];
    short* XL = XH + 64 * 72;
    // convert + stage into LDS; accumulate rowsums
#pragma unroll
    for (int i = 0; i < 4; i++) {
      const int ch = (i << 4) + u;
      rsp[i] += vv[i][0] + vv[i][1] + vv[i][2] + vv[i][3];
      short4v hv, lv;
#pragma unroll
      for (int j = 0; j < 4; j++) {
        hv[j] = bf16t(vv[i][j]);
        lv[j] = bf16t(vv[i][j] - bf16f(hv[j]));
      }
      *(short4v*)&XH[ch * 72 + (quad << 2)] = hv;
      *(short4v*)&XL[ch * 72 + (quad << 2)] = lv;
    }
    // prefetch next chunk (stays outstanding across the raw barrier)
    if (c < 7) {
      const int p0 = pcbase + ((c + 1) << 6);
#pragma unroll
      for (int i = 0; i < 4; i++)
        vv[i] = *(const f32x4*)&xb[((size_t)chan[(i << 4) + u] << 12) + p0 +
                                   (quad << 2)];
    }
    lds_barrier();
    // compute: wave w rows (A) x all hb rows (B)
#pragma unroll
    for (int s = 0; s < 2; s++) {
      const int ko = (s << 5) + (q << 3);
      const short8 ah = *(const short8*)&XH[((w << 4) + n15) * 72 + ko];
      const short8 al = *(const short8*)&XL[((w << 4) + n15) * 72 + ko];
#pragma unroll
      for (int hb = 0; hb < 4; hb++) {
        const short8 bh = *(const short8*)&XH[((hb << 4) + n15) * 72 + ko];
        const short8 bl = *(const short8*)&XL[((hb << 4) + n15) * 72 + ko];
        acc[hb] = MFMA16(ah, bh, acc[hb], 0, 0, 0);
        acc[hb] = MFMA16(ah, bl, acc[hb], 0, 0, 0);
        acc[hb] = MFMA16(al, bh, acc[hb], 0, 0, 0);
      }
    }
  }
  // rowsums: reduce across the 16 quad-lanes (same u), one atomic per channel
#pragma unroll
  for (int i = 0; i < 4; i++) {
    float r = rsp[i];
    r += __shfl_xor(r, 1);
    r += __shfl_xor(r, 2);
    r += __shfl_xor(r, 4);
    r += __shfl_xor(r, 8);
    if (quad == 0) atomicAdd(&rsum[(b << 6) + (i << 4) + u], r);
  }
  // sigma: C-layout row m=4q+r -> g = 16w+4q+r; col n15 -> h = 16hb+n15
  float* sb = sigw + ((size_t)b << 12);
#pragma unroll
  for (int hb = 0; hb < 4; hb++)
#pragma unroll
    for (int r = 0; r < 4; r++)
      atomicAdd(&sb[(((w << 4) + (q << 2) + r) << 6) + (hb << 4) + n15],
                acc[hb][r]);
}

// ---------------------------------------------------------------------------
// Stage 2 (MFMA): mean + sigma_N + Newton-Schulz (T=5), 1 block/batch.
// Every NS matrix is a polynomial in symmetric sigma_N -> symmetric, so the
// row-row MFMA pattern (C = A * B_sym) needs no transposes. Operands live in
// LDS as bf16 hi/lo (3-term products, ~2^-17 rel err); the P state itself
// stays fp32 in registers (each thread owns its 16 acc-coord elements for the
// whole iteration, so P never round-trips through LDS/global).
// First NS iter folded analytically: P1 = 1.5 I - 0.5 sigma_N.
// LDS: PA (P, then Ta=P@P) | TB (SN fp32 at init, then Tb=P@SN) | SN bf16.
// ---------------------------------------------------------------------------
#define NSTR 72

__global__ __launch_bounds__(256) void k_ns(const float* __restrict__ sigw,
                                            const float* __restrict__ rsum,
                                            float* __restrict__ meanw,
                                            float* __restrict__ wmw) {
  __shared__ __align__(16) short PA[2 * 64 * NSTR];
  __shared__ __align__(16) short TB[2 * 64 * NSTR];
  __shared__ __align__(16) short SB[2 * 64 * NSTR];
  __shared__ float ml[64];
  __shared__ float tr_s;
  const int tid = threadIdx.x;
  const int b = blockIdx.x;
  const int w = tid >> 6, lane = tid & 63;
  const int q = lane >> 4, n15 = lane & 15;

  float* SNf = (float*)TB;  // 16 KB fp32 view, alive only during init

  if (tid < 64) {
    const float mu = rsum[(b << 6) + tid] * (1.f / 16384.f);
    ml[tid] = mu;
    meanw[(b << 6) + tid] = mu;
  }
  __syncthreads();
#pragma unroll
  for (int i = 0; i < 16; i++) {
    const int e = (i << 8) + tid;
    const int g = e >> 6, h = e & 63;
    SNf[e] = sigw[(b << 12) + e] * (1.f / 16384.f) - ml[g] * ml[h];
  }
  __syncthreads();
  if (tid < 64) {
    float d = SNf[tid * 65];
#pragma unroll
    for (int off = 32; off; off >>= 1) d += __shfl_down(d, off);
    if (tid == 0) tr_s = 1.f / d;
  }
  __syncthreads();
  const float trinv = tr_s;

  // Build SN bf16 hi/lo and P1 = 1.5I - 0.5*SN (bf16 tiles at e-coords).
#pragma unroll
  for (int i = 0; i < 16; i++) {
    const int e = (i << 8) + tid;
    const int g = e >> 6, h = e & 63;
    const float sv = SNf[e] * trinv;
    const short sh = bf16t(sv);
    SB[g * NSTR + h] = sh;
    SB[64 * NSTR + g * NSTR + h] = bf16t(sv - bf16f(sh));
    const float pv = ((g == h) ? 1.5f : 0.f) - 0.5f * sv;
    const short ph = bf16t(pv);
    PA[g * NSTR + h] = ph;
    PA[64 * NSTR + g * NSTR + h] = bf16t(pv - bf16f(ph));
  }
  // P1 fp32 at this thread's acc coords (before TB/SNf gets overwritten).
  float pr[4][4];
#pragma unroll
  for (int ct = 0; ct < 4; ct++)
#pragma unroll
    for (int r = 0; r < 4; r++) {
      const int row = (w << 4) + (q << 2) + r, col = (ct << 4) + n15;
      pr[ct][r] =
          ((row == col) ? 1.5f : 0.f) - 0.5f * SNf[(row << 6) + col] * trinv;
    }
  __syncthreads();

  for (int it = 0; it < 4; it++) {
    // phase 1: aP2 = P@P, aPS = P@SN
    f32x4 aP2[4], aPS[4];
#pragma unroll
    for (int t = 0; t < 4; t++) {
      aP2[t] = (f32x4){0.f, 0.f, 0.f, 0.f};
      aPS[t] = (f32x4){0.f, 0.f, 0.f, 0.f};
    }
#pragma unroll
    for (int s = 0; s < 2; s++) {
      const int ko = (s << 5) + (q << 3);
      const short8 ah = *(const short8*)&PA[((w << 4) + n15) * NSTR + ko];
      const short8 al =
          *(const short8*)&PA[64 * NSTR + ((w << 4) + n15) * NSTR + ko];
#pragma unroll
      for (int ct = 0; ct < 4; ct++) {
        const short8 bh = *(const short8*)&PA[((ct << 4) + n15) * NSTR + ko];
        const short8 bl =
            *(const short8*)&PA[64 * NSTR + ((ct << 4) + n15) * NSTR + ko];
        aP2[ct] = MFMA16(ah, bh, aP2[ct], 0, 0, 0);
        aP2[ct] = MFMA16(ah, bl, aP2[ct], 0, 0, 0);
        aP2[ct] = MFMA16(al, bh, aP2[ct], 0, 0, 0);
        const short8 ch = *(const short8*)&SB[((ct << 4) + n15) * NSTR + ko];
        const short8 cl =
            *(const short8*)&SB[64 * NSTR + ((ct << 4) + n15) * NSTR + ko];
        aPS[ct] = MFMA16(ah, ch, aPS[ct], 0, 0, 0);
        aPS[ct] = MFMA16(ah, cl, aPS[ct], 0, 0, 0);
        aPS[ct] = MFMA16(al, ch, aPS[ct], 0, 0, 0);
      }
    }
    __syncthreads();  // phase-1 reads of PA done before overwrite
    // Ta -> PA, Tb -> TB (bf16 hi/lo at acc coords)
#pragma unroll
    for (int ct = 0; ct < 4; ct++)
#pragma unroll
      for (int r = 0; r < 4; r++) {
        const int row = (w << 4) + (q << 2) + r, col = (ct << 4) + n15;
        const float v1 = aP2[ct][r];
        const short h1 = bf16t(v1);
        PA[row * NSTR + col] = h1;
        PA[64 * NSTR + row * NSTR + col] = bf16t(v1 - bf16f(h1));
        const float v2 = aPS[ct][r];
        const short h2 = bf16t(v2);
        TB[row * NSTR + col] = h2;
        TB[64 * NSTR + row * NSTR + col] = bf16t(v2 - bf16f(h2));
      }
    __syncthreads();
    // phase 2: aT3 = Ta@Tb
    f32x4 aT3[4];
#pragma unroll
    for (int t = 0; t < 4; t++) aT3[t] = (f32x4){0.f, 0.f, 0.f, 0.f};
#pragma unroll
    for (int s = 0; s < 2; s++) {
      const int ko = (s << 5) + (q << 3);
      const short8 ah = *(const short8*)&PA[((w << 4) + n15) * NSTR + ko];
      const short8 al =
          *(const short8*)&PA[64 * NSTR + ((w << 4) + n15) * NSTR + ko];
#pragma unroll
      for (int ct = 0; ct < 4; ct++) {
        const short8 bh = *(const short8*)&TB[((ct << 4) + n15) * NSTR + ko];
        const short8 bl =
            *(const short8*)&TB[64 * NSTR + ((ct << 4) + n15) * NSTR + ko];
        aT3[ct] = MFMA16(ah, bh, aT3[ct], 0, 0, 0);
        aT3[ct] = MFMA16(ah, bl, aT3[ct], 0, 0, 0);
        aT3[ct] = MFMA16(al, bh, aT3[ct], 0, 0, 0);
      }
    }
    __syncthreads();  // phase-2 reads of PA done before overwrite
    // P update (fp32 in regs); last iter folds wm = P * sqrt(trinv)
    const bool last = (it == 3);
    const float sc = sqrtf(trinv);
#pragma unroll
    for (int ct = 0; ct < 4; ct++)
#pragma unroll
      for (int r = 0; r < 4; r++) {
        const int row = (w << 4) + (q << 2) + r, col = (ct << 4) + n15;
        const float pn = 1.5f * pr[ct][r] - 0.5f * aT3[ct][r];
        pr[ct][r] = pn;
        if (last) {
          wmw[(b << 12) + (row << 6) + col] = pn * sc;
        } else {
          const short h1 = bf16t(pn);
          PA[row * NSTR + col] = h1;
          PA[64 * NSTR + row * NSTR + col] = bf16t(pn - bf16f(h1));
        }
      }
    if (!last) __syncthreads();
  }
}

// ---------------------------------------------------------------------------
// Stage 3+4 fused: per-block redundant batch sqrtvar (ddof=1, two-pass, reads
// are L2-resident) computed into Sv (aliased onto Al's LDS, dead until mm64);
// then gamma = triu(wir)+triu(wir,1)^T; A = gamma@wm (fp32);
// ofs = mean + eps2*svm - A@mean; A exported as bf16 hi/lo pair.
// ---------------------------------------------------------------------------
__global__ __launch_bounds__(256) void k_gA(
    const float* __restrict__ wmw, const float* __restrict__ meanw,
    const float* __restrict__ eps1, const float* __restrict__ eps2,
    short* __restrict__ Ahl, float* __restrict__ ofsw) {
  __shared__ __align__(16) float Wl[4096];
  __shared__ __align__(16) float Gm[4096];
  __shared__ __align__(16) float Al[4096];  // doubles as Sv before mm64
  __shared__ float ml[64];
  __shared__ float svml[64];
  const int tid = threadIdx.x;
  const int b = blockIdx.x;
  float* Sv = Al;

  // sqrtvar(wm) across batch: thread owns 16 elements, two-pass for precision
#pragma unroll
  for (int i = 0; i < 16; i++) {
    const int e = (i << 8) + tid;
    float vv[32];
    float s = 0.f;
#pragma unroll
    for (int p = 0; p < 32; p++) {
      vv[p] = wmw[(p << 12) + e];
      s += vv[p];
    }
    const float mu = s * (1.f / 32.f);
    float s2 = 0.f;
#pragma unroll
    for (int p = 0; p < 32; p++) {
      const float d = vv[p] - mu;
      s2 = fmaf(d, d, s2);
    }
    Sv[e] = sqrtf(s2 * (1.f / 31.f) + 1e-5f);
  }
  // sqrtvar(mean) across batch + own-batch mean row
  if (tid < 64) {
    ml[tid] = meanw[(b << 6) + tid];
    float vv[32];
    float s = 0.f;
#pragma unroll
    for (int p = 0; p < 32; p++) {
      vv[p] = meanw[(p << 6) + tid];
      s += vv[p];
    }
    const float mu = s * (1.f / 32.f);
    float s2 = 0.f;
#pragma unroll
    for (int p = 0; p < 32; p++) {
      const float d = vv[p] - mu;
      s2 = fmaf(d, d, s2);
    }
    svml[tid] = sqrtf(s2 * (1.f / 31.f) + 1e-5f);
  }
#pragma unroll
  for (int i = 0; i < 16; i++) {
    const int e = (i << 8) + tid;
    Wl[e] = wmw[(b << 12) + e];
  }
  __syncthreads();
#pragma unroll
  for (int i = 0; i < 16; i++) {
    const int e = (i << 8) + tid;
    const int g = e >> 6, h = e & 63;
    const int eu = (h >= g) ? e : ((h << 6) + g);  // mirror lower from upper
    Gm[e] = Wl[eu] + eps1[(b << 12) + eu] * Sv[eu];
  }
  __syncthreads();
  mm64(Gm, Wl, Al, tid);  // Al = gamma @ wm (Gm bitwise symmetric); kills Sv
  short* Ab = Ahl + ((size_t)b << 13);
#pragma unroll
  for (int i = 0; i < 16; i++) {
    const int e = (i << 8) + tid;
    const float a = Al[e];
    const short h2 = bf16t(a);
    Ab[e] = h2;
    Ab[4096 + e] = bf16t(a - bf16f(h2));
  }
  if (tid < 64) {
    float dot = 0.f;
    for (int h = 0; h < 64; h++) dot = fmaf(Al[(tid << 6) + h], ml[h], dot);
    ofsw[(b << 6) + tid] = ml[tid] + eps2[(b << 6) + tid] * svml[tid] - dot;
  }
}

// ---------------------------------------------------------------------------
// Stage 5 (MFMA): out[b, idx[4g+k], p] = sum_h A[g,h] x[b, idx[4h+k], p] + ofs.
// block 256 = 4 waves; wave w owns g-rows 16w..16w+15; A-frags loaded ONCE
// from global into registers (as the MFMA *B*-operand). X staged transposed
// as bf16 hi/lo [px64][h64] stride 72, converted ONCE at staging time,
// double-buffered. Operand order D = X^T(A-op) x A(B-op) puts px in the acc
// register index -> f32x4 stores. Raw barrier per chunk: prefetch loads and
// output stores stay in flight across it.
// ---------------------------------------------------------------------------
__global__ __launch_bounds__(256, 4) void k_apply(const float* __restrict__ x,
                                                  const int* __restrict__ idx,
                                                  const short* __restrict__ Ahl,
                                                  const float* __restrict__ ofsw,
                                                  float* __restrict__ out) {
  __shared__ __align__(16) short XT[2][2 * 64 * 72];  // per buf: hi | lo
  __shared__ int chan[64];
  const int tid = threadIdx.x;
  const int w = tid >> 6, lane = tid & 63;
  const int q = lane >> 4, n15 = lane & 15;
  const int blk = blockIdx.x;
  const int b = blk >> 5, k = (blk >> 3) & 3, pc = blk & 7;

  if (tid < 64) chan[tid] = idx[(tid << 2) + k];

  // A-matrix fragments direct from global (lane n15 = A-row g within gb=w)
  const short* Ab = Ahl + ((size_t)b << 13);
  short8 ah[2], al[2];
#pragma unroll
  for (int s = 0; s < 2; s++) {
    const int o = (((w << 4) + n15) << 6) + (s << 5) + (q << 3);
    ah[s] = *(const short8*)&Ab[o];
    al[s] = *(const short8*)&Ab[4096 + o];
  }
  const float of = ofsw[(b << 6) + (w << 4) + n15];
  __syncthreads();

  const float* xb = x + ((size_t)b << 20);
  float* outb = out + ((size_t)b << 20);
  const int pcbase = pc << 9;

  float v[16];
#pragma unroll
  for (int j = 0; j < 16; j++)  // prolog: chunk 0 (row chan[16w+j], px=lane)
    v[j] = xb[((size_t)chan[(w << 4) + j] << 12) + pcbase + lane];

  for (int c = 0; c < 8; c++) {
    short* XH = &XT[c & 1][0];
    short* XL = XH + 64 * 72;
    // stage transposed bf16 hi/lo: row px=lane, cols h = 16w..16w+15
#pragma unroll
    for (int jj = 0; jj < 4; jj++) {
      short4v hv, lv;
#pragma unroll
      for (int j = 0; j < 4; j++) {
        const float f = v[(jj << 2) + j];
        hv[j] = bf16t(f);
        lv[j] = bf16t(f - bf16f(hv[j]));
      }
      *(short4v*)&XH[lane * 72 + (w << 4) + (jj << 2)] = hv;
      *(short4v*)&XL[lane * 72 + (w << 4) + (jj << 2)] = lv;
    }
    if (c < 7) {
      const int p0n = pcbase + ((c + 1) << 6);
#pragma unroll
      for (int j = 0; j < 16; j++)
        v[j] = xb[((size_t)chan[(w << 4) + j] << 12) + p0n + lane];
    }
    lds_barrier();

    const int p0 = pcbase + (c << 6);
    f32x4 acc[4];
#pragma unroll
    for (int nb = 0; nb < 4; nb++) acc[nb] = (f32x4){of, of, of, of};
#pragma unroll
    for (int s = 0; s < 2; s++) {
#pragma unroll
      for (int nb = 0; nb < 4; nb++) {
        const int ro = ((nb << 4) + n15) * 72 + (s << 5) + (q << 3);
        const short8 xh = *(const short8*)&XH[ro];
        const short8 xl = *(const short8*)&XL[ro];
        acc[nb] = MFMA16(xh, ah[s], acc[nb], 0, 0, 0);
        acc[nb] = MFMA16(xl, ah[s], acc[nb], 0, 0, 0);
        acc[nb] = MFMA16(xh, al[s], acc[nb], 0, 0, 0);
      }
    }
    // stores: C-layout row = q*4+reg = px within tile nb, col = n15 = g.
#pragma unroll
    for (int nb = 0; nb < 4; nb++) {
      *(f32x4*)&outb[((size_t)chan[(w << 4) + n15] << 12) + p0 + (nb << 4) +
                     (q << 2)] = acc[nb];
    }
  }
}

// ---------------------------------------------------------------------------
// ws layout (floats): sigw@0 (131072, zeroed) | rsum@131072 (2048, zeroed)
//  | meanw@133120 (2048) | wmw@135168 (131072) | ofsw@270400 (2048)
//  | Ahl@272448 (short[262144]).
// ---------------------------------------------------------------------------
extern "C" void kernel_launch(void* const* d_in, const int* in_sizes, int n_in,
                              void* d_out, int out_size, void* d_ws,
                              size_t ws_size, hipStream_t stream) {
  const float* x = (const float*)d_in[0];
  const int* idx = (const int*)d_in[1];
  const float* eps1 = (const float*)d_in[2];
  const float* eps2 = (const float*)d_in[3];
  float* out = (float*)d_out;
  float* ws = (float*)d_ws;

  float* sigw = ws;
  float* rsum = ws + 131072;
  float* meanw = ws + 133120;
  float* wmw = ws + 135168;
  float* ofsw = ws + 270400;
  short* Ahl = (short*)(ws + 272448);

  hipMemsetAsync(ws, 0, (131072 + 2048) * sizeof(float), stream);
  k_stats<<<1024, 256, 0, stream>>>(x, idx, sigw, rsum);
  k_ns<<<32, 256, 0, stream>>>(sigw, rsum, meanw, wmw);
  k_gA<<<32, 256, 0, stream>>>(wmw, meanw, eps1, eps2, Ahl, ofsw);
  k_apply<<<1024, 256, 0, stream>>>(x, idx, Ahl, ofsw, out);
}